// Round 5
// baseline (351.445 us; speedup 1.0000x reference)
//
#include <hip/hip_runtime.h>
#include <math.h>

#define NA 360
#define NP 512
#define NB 16
#define IMG 512
#define PSA 514              // Path A: p' in [0,513], 64 B/point (paired taps)
#define PSB 515              // Path B: q' in [0,514], 32 B/point (single tap)

typedef unsigned int uint32;
typedef __fp16 half2 __attribute__((ext_vector_type(2)));   // matches builtin V2h

static __device__ __forceinline__ half2 u2h(uint32 u) {
    union { uint32 u; half2 h; } v; v.u = u; return v.h;
}
static __device__ __forceinline__ uint32 pk(float a, float b) {
    union { half2 h; uint32 u; } v;
    v.h = __builtin_amdgcn_cvt_pkrtz(a, b);
    return v.u;
}

#if __has_builtin(__builtin_amdgcn_fdot2)
static __device__ __forceinline__ float dot2(half2 w, half2 v, float acc) {
    return __builtin_amdgcn_fdot2(w, v, acc, false);
}
#else
static __device__ __forceinline__ float dot2(half2 w, half2 v, float acc) {
    return fmaf((float)w.x, (float)v.x, fmaf((float)w.y, (float)v.y, acc));
}
#endif

static __device__ __forceinline__ void write_tab(const float* thetas,
                                                 const float* positions,
                                                 float4* tab, int a) {
    double th = (double)thetas[a];
    double p0 = (double)positions[0];
    double dp = (double)positions[1] - p0;
    tab[a] = make_float4((float)(cos(th) / dp), (float)(sin(th) / dp),
                         (float)(-p0 / dp), 0.0f);
}

// ---------------- Path A: paired taps, 64 B/(a,p'), 11.84 MB ----------------
__global__ void stageA(const float* __restrict__ sino,
                       const float* __restrict__ thetas,
                       const float* __restrict__ positions,
                       float4* __restrict__ tab,
                       uint32* __restrict__ st) {
    if (blockIdx.x == gridDim.x - 1) {
        int a = threadIdx.x;
        if (a < NA) write_tab(thetas, positions, tab, a);
        int a2 = threadIdx.x + 256;
        if (a2 < NA) write_tab(thetas, positions, tab, a2);
        return;
    }
    int idx = blockIdx.x * 256 + threadIdx.x;   // idx = a*PSA + p'
    if (idx >= NA * PSA) return;
    int a  = idx / PSA;
    int pp = idx - a * PSA;
    int p0 = pp - 1;
    uint32 r[16];
#pragma unroll
    for (int b = 0; b < NB; ++b) {
        const float* row = sino + ((size_t)b * NA + a) * NP;
        float f0 = (p0 >= 0 && p0 < NP) ? row[p0] : 0.0f;
        float f1 = (pp < NP) ? row[pp] : 0.0f;
        r[b] = pk(f0, f1);
    }
    uint4* dst = (uint4*)(st + (size_t)idx * 16);
#pragma unroll
    for (int k = 0; k < 4; ++k)
        dst[k] = make_uint4(r[4 * k], r[4 * k + 1], r[4 * k + 2], r[4 * k + 3]);
}

__launch_bounds__(256)
__global__ void backprojectA(const uint32* __restrict__ st,
                             const float4* __restrict__ tab,
                             float* __restrict__ out) {
    const int x = blockIdx.x * 64 + threadIdx.x;
    const int y = blockIdx.y * 4 + threadIdx.y;
    const float xs = (float)x - ((IMG - 1) * 0.5f);
    const float ys = (float)y - ((IMG - 1) * 0.5f);
    float acc[NB];
#pragma unroll
    for (int b = 0; b < NB; ++b) acc[b] = 0.0f;

#pragma unroll 2
    for (int a = 0; a < NA; ++a) {
        const float4 t = tab[a];
        float fidx = fmaf(xs, t.x, fmaf(ys, t.y, t.z));
        fidx = fminf(fmaxf(fidx, -1.0f), 512.0f);   // pads absorb all OOB cases
        const float fl = floorf(fidx);
        const float w = fidx - fl;
        const half2 wp = u2h(pk(1.0f - w, w));
        const int p1i = (int)fl + 1;                // [0,513]
        const uint4* q = (const uint4*)((const char*)st +
                         ((size_t)a * (PSA * 64)) + ((size_t)p1i << 6));
        const uint4 d0 = q[0], d1 = q[1], d2 = q[2], d3 = q[3];
        const uint32 u[16] = {d0.x, d0.y, d0.z, d0.w, d1.x, d1.y, d1.z, d1.w,
                              d2.x, d2.y, d2.z, d2.w, d3.x, d3.y, d3.z, d3.w};
#pragma unroll
        for (int b = 0; b < NB; ++b)
            acc[b] = dot2(wp, u2h(u[b]), acc[b]);
    }

    const size_t pix = (size_t)y * IMG + x;
#pragma unroll
    for (int b = 0; b < NB; ++b)
        out[(size_t)b * (IMG * IMG) + pix] = acc[b];
}

// ------------- Path B: single taps, 32 B/(a,q'), 5.93 MB (fallback) ---------
__global__ void stageB(const float* __restrict__ sino,
                       const float* __restrict__ thetas,
                       const float* __restrict__ positions,
                       float4* __restrict__ tab,
                       uint32* __restrict__ st) {
    if (blockIdx.x == gridDim.x - 1) {
        int a = threadIdx.x;
        if (a < NA) write_tab(thetas, positions, tab, a);
        int a2 = threadIdx.x + 256;
        if (a2 < NA) write_tab(thetas, positions, tab, a2);
        return;
    }
    int idx = blockIdx.x * 256 + threadIdx.x;   // idx = a*PSB + q'
    if (idx >= NA * PSB) return;
    int a = idx / PSB;
    int q = (idx - a * PSB) - 1;                // stored value = s[q], pads at ends
    uint32 r[8];
#pragma unroll
    for (int k = 0; k < 8; ++k) {
        const float* r0 = sino + ((size_t)(2 * k) * NA + a) * NP;
        const float* r1 = sino + ((size_t)(2 * k + 1) * NA + a) * NP;
        float f0 = (q >= 0 && q < NP) ? r0[q] : 0.0f;
        float f1 = (q >= 0 && q < NP) ? r1[q] : 0.0f;
        r[k] = pk(f0, f1);
    }
    uint4* dst = (uint4*)(st + (size_t)idx * 8);
    dst[0] = make_uint4(r[0], r[1], r[2], r[3]);
    dst[1] = make_uint4(r[4], r[5], r[6], r[7]);
}

__launch_bounds__(256)
__global__ void backprojectB(const uint32* __restrict__ st,
                             const float4* __restrict__ tab,
                             float* __restrict__ out) {
    const int x = blockIdx.x * 64 + threadIdx.x;
    const int y = blockIdx.y * 4 + threadIdx.y;
    const float xs = (float)x - ((IMG - 1) * 0.5f);
    const float ys = (float)y - ((IMG - 1) * 0.5f);
    float acc[NB];
#pragma unroll
    for (int b = 0; b < NB; ++b) acc[b] = 0.0f;

#pragma unroll 2
    for (int a = 0; a < NA; ++a) {
        const float4 t = tab[a];
        float fidx = fmaf(xs, t.x, fmaf(ys, t.y, t.z));
        fidx = fminf(fmaxf(fidx, -1.0f), 512.0f);
        const float fl = floorf(fidx);
        const float w = fidx - fl;
        const half2 wp = u2h(pk(1.0f - w, w));
        const int qs = (int)fl + 1;                 // chunk0: s[fl], chunk1: s[fl+1]
        const uint4* q = (const uint4*)((const char*)st +
                         ((size_t)a * (PSB * 32)) + ((size_t)qs << 5));
        const uint4 c00 = q[0], c01 = q[1];         // taps s[fl], batches 0..15
        const uint4 c10 = q[2], c11 = q[3];         // taps s[fl+1] (next point)
        const uint32 c0[8] = {c00.x, c00.y, c00.z, c00.w, c01.x, c01.y, c01.z, c01.w};
        const uint32 c1[8] = {c10.x, c10.y, c10.z, c10.w, c11.x, c11.y, c11.z, c11.w};
#pragma unroll
        for (int k = 0; k < 8; ++k) {
            uint32 plo = __builtin_amdgcn_perm(c0[k], c1[k], 0x01000504u);
            uint32 phi = __builtin_amdgcn_perm(c0[k], c1[k], 0x03020706u);
            acc[2 * k]     = dot2(wp, u2h(plo), acc[2 * k]);
            acc[2 * k + 1] = dot2(wp, u2h(phi), acc[2 * k + 1]);
        }
    }

    const size_t pix = (size_t)y * IMG + x;
#pragma unroll
    for (int b = 0; b < NB; ++b)
        out[(size_t)b * (IMG * IMG) + pix] = acc[b];
}

// ----------------------------------------------------------------------------
extern "C" void kernel_launch(void* const* d_in, const int* in_sizes, int n_in,
                              void* d_out, int out_size, void* d_ws, size_t ws_size,
                              hipStream_t stream) {
    const float* sino      = (const float*)d_in[0];
    const float* thetas    = (const float*)d_in[1];
    const float* positions = (const float*)d_in[2];
    float* out = (float*)d_out;

    float4* tab = (float4*)d_ws;
    uint32* st  = (uint32*)((char*)d_ws + 8192);

    const size_t needA = 8192 + (size_t)NA * PSA * 64;   // ~11.85 MB
    if (ws_size >= needA) {
        const int nb = (NA * PSA + 255) / 256 + 1;
        stageA<<<dim3(nb), dim3(256), 0, stream>>>(sino, thetas, positions, tab, st);
        backprojectA<<<dim3(IMG / 64, IMG / 4), dim3(64, 4), 0, stream>>>(st, tab, out);
    } else {
        const int nb = (NA * PSB + 255) / 256 + 1;
        stageB<<<dim3(nb), dim3(256), 0, stream>>>(sino, thetas, positions, tab, st);
        backprojectB<<<dim3(IMG / 64, IMG / 4), dim3(64, 4), 0, stream>>>(st, tab, out);
    }
}

// Round 6
// 271.357 us; speedup vs baseline: 1.2951x; 1.2951x over previous
//
#include <hip/hip_runtime.h>
#include <math.h>

#define NA 360
#define NP 512
#define NB 16
#define IMG 512
#define PS 514               // p' in [0,513]; point p' holds taps (s[p'-1], s[p'])

typedef unsigned int uint32;
typedef __fp16 half2 __attribute__((ext_vector_type(2)));   // builtin V2h type

static __device__ __forceinline__ half2 u2h(uint32 u) {
    union { uint32 u; half2 h; } v; v.u = u; return v.h;
}
static __device__ __forceinline__ uint32 pk(float a, float b) {
    union { half2 h; uint32 u; } v;
    v.h = __builtin_amdgcn_cvt_pkrtz(a, b);
    return v.u;
}

#if __has_builtin(__builtin_amdgcn_fdot2)
static __device__ __forceinline__ float dot2(half2 w, half2 v, float acc) {
    return __builtin_amdgcn_fdot2(w, v, acc, false);
}
#else
static __device__ __forceinline__ float dot2(half2 w, half2 v, float acc) {
    return fmaf((float)w.x, (float)v.x, fmaf((float)w.y, (float)v.y, acc));
}
#endif

static __device__ __forceinline__ void write_tab(const float* thetas,
                                                 const float* positions,
                                                 float4* tab, int a) {
    double th = (double)thetas[a];
    double p0 = (double)positions[0];
    double dp = (double)positions[1] - p0;
    tab[a] = make_float4((float)(cos(th) / dp), (float)(sin(th) / dp),
                         (float)(-p0 / dp), 0.0f);
}

// Staging: [b][a][p] f32 -> 4 planes, plane k: [a][p'] of uint4 holding
// f16 tap-pairs for batches 4k..4k+3. 16 B per point per plane.
__global__ void stage(const float* __restrict__ sino,
                      const float* __restrict__ thetas,
                      const float* __restrict__ positions,
                      float4* __restrict__ tab,
                      uint4* __restrict__ st) {
    if (blockIdx.x == gridDim.x - 1) {
        int a = threadIdx.x;
        if (a < NA) write_tab(thetas, positions, tab, a);
        int a2 = threadIdx.x + 256;
        if (a2 < NA) write_tab(thetas, positions, tab, a2);
        return;
    }
    int idx = blockIdx.x * 256 + threadIdx.x;   // idx = a*PS + p'
    if (idx >= NA * PS) return;
    int a  = idx / PS;
    int pp = idx - a * PS;
    int p0 = pp - 1;
    uint32 r[16];
#pragma unroll
    for (int b = 0; b < NB; ++b) {
        const float* row = sino + ((size_t)b * NA + a) * NP;
        float f0 = (p0 >= 0 && p0 < NP) ? row[p0] : 0.0f;
        float f1 = (pp < NP) ? row[pp] : 0.0f;
        r[b] = pk(f0, f1);
    }
#pragma unroll
    for (int k = 0; k < 4; ++k)
        st[(size_t)k * (NA * PS) + idx] =
            make_uint4(r[4 * k], r[4 * k + 1], r[4 * k + 2], r[4 * k + 3]);
}

// One thread = one (x,y) pixel, 16 batches. Block 16x16 so a wave (16x * 4y)
// spans only ~17 points -> each dwordx4 gather touches ~4 cache lines.
__launch_bounds__(256)
__global__ void backproject(const uint4* __restrict__ st,
                            const float4* __restrict__ tab,
                            float* __restrict__ out) {
    const int x = blockIdx.x * 16 + threadIdx.x;
    const int y = blockIdx.y * 16 + threadIdx.y;
    const float xs = (float)x - ((IMG - 1) * 0.5f);
    const float ys = (float)y - ((IMG - 1) * 0.5f);
    const uint4* __restrict__ pl0 = st;
    const uint4* __restrict__ pl1 = st + (size_t)(NA * PS);
    const uint4* __restrict__ pl2 = st + (size_t)(2 * NA * PS);
    const uint4* __restrict__ pl3 = st + (size_t)(3 * NA * PS);
    float acc[NB];
#pragma unroll
    for (int b = 0; b < NB; ++b) acc[b] = 0.0f;

#pragma unroll 2
    for (int a = 0; a < NA; ++a) {
        const float4 t = tab[a];
        float fidx = fmaf(xs, t.x, fmaf(ys, t.y, t.z));
        fidx = fminf(fmaxf(fidx, -1.0f), 512.0f);   // pads absorb all OOB cases
        const float fl = floorf(fidx);
        const float w = fidx - fl;
        const half2 wp = u2h(pk(1.0f - w, w));
        const int idx = a * PS + ((int)fl + 1);     // common voffset, 4 s-bases
        const uint4 d0 = pl0[idx];
        const uint4 d1 = pl1[idx];
        const uint4 d2 = pl2[idx];
        const uint4 d3 = pl3[idx];
        acc[0]  = dot2(wp, u2h(d0.x), acc[0]);
        acc[1]  = dot2(wp, u2h(d0.y), acc[1]);
        acc[2]  = dot2(wp, u2h(d0.z), acc[2]);
        acc[3]  = dot2(wp, u2h(d0.w), acc[3]);
        acc[4]  = dot2(wp, u2h(d1.x), acc[4]);
        acc[5]  = dot2(wp, u2h(d1.y), acc[5]);
        acc[6]  = dot2(wp, u2h(d1.z), acc[6]);
        acc[7]  = dot2(wp, u2h(d1.w), acc[7]);
        acc[8]  = dot2(wp, u2h(d2.x), acc[8]);
        acc[9]  = dot2(wp, u2h(d2.y), acc[9]);
        acc[10] = dot2(wp, u2h(d2.z), acc[10]);
        acc[11] = dot2(wp, u2h(d2.w), acc[11]);
        acc[12] = dot2(wp, u2h(d3.x), acc[12]);
        acc[13] = dot2(wp, u2h(d3.y), acc[13]);
        acc[14] = dot2(wp, u2h(d3.z), acc[14]);
        acc[15] = dot2(wp, u2h(d3.w), acc[15]);
    }

    const size_t pix = (size_t)y * IMG + x;
#pragma unroll
    for (int b = 0; b < NB; ++b)
        out[(size_t)b * (IMG * IMG) + pix] = acc[b];
}

extern "C" void kernel_launch(void* const* d_in, const int* in_sizes, int n_in,
                              void* d_out, int out_size, void* d_ws, size_t ws_size,
                              hipStream_t stream) {
    const float* sino      = (const float*)d_in[0];
    const float* thetas    = (const float*)d_in[1];
    const float* positions = (const float*)d_in[2];
    float* out = (float*)d_out;

    float4* tab = (float4*)d_ws;                     // 360 * 16 B
    uint4*  st  = (uint4*)((char*)d_ws + 8192);      // 4 planes * 2.96 MB = 11.84 MB

    const int nb = (NA * PS + 255) / 256 + 1;        // +1 block computes tab
    stage<<<dim3(nb), dim3(256), 0, stream>>>(sino, thetas, positions, tab, st);
    backproject<<<dim3(IMG / 16, IMG / 16), dim3(16, 16), 0, stream>>>(st, tab, out);
}

// Round 7
// 238.431 us; speedup vs baseline: 1.4740x; 1.1381x over previous
//
#include <hip/hip_runtime.h>
#include <math.h>

#define NA 360
#define NP 512
#define NB 16
#define IMG 512
#define PS 514               // p' in [0,513]; point p' holds taps (s[p'-1], s[p'])

typedef unsigned int uint32;
typedef __fp16 half2 __attribute__((ext_vector_type(2)));   // builtin V2h type

static __device__ __forceinline__ half2 u2h(uint32 u) {
    union { uint32 u; half2 h; } v; v.u = u; return v.h;
}
static __device__ __forceinline__ uint32 pk(float a, float b) {
    union { half2 h; uint32 u; } v;
    v.h = __builtin_amdgcn_cvt_pkrtz(a, b);
    return v.u;
}

#if __has_builtin(__builtin_amdgcn_fdot2)
static __device__ __forceinline__ float dot2(half2 w, half2 v, float acc) {
    return __builtin_amdgcn_fdot2(w, v, acc, false);
}
#else
static __device__ __forceinline__ float dot2(half2 w, half2 v, float acc) {
    return fmaf((float)w.x, (float)v.x, fmaf((float)w.y, (float)v.y, acc));
}
#endif

static __device__ __forceinline__ void write_tab(const float* thetas,
                                                 const float* positions,
                                                 float4* tab, int a) {
    double th = (double)thetas[a];
    double p0 = (double)positions[0];
    double dp = (double)positions[1] - p0;
    tab[a] = make_float4((float)(cos(th) / dp), (float)(sin(th) / dp),
                         (float)(-p0 / dp), 0.0f);
}

// Staging: [b][a][p] f32 -> 4 planes, plane k: [a][p'] of uint4 holding
// f16 tap-pairs for batches 4k..4k+3. 16 B per point per plane.
__global__ void stage(const float* __restrict__ sino,
                      const float* __restrict__ thetas,
                      const float* __restrict__ positions,
                      float4* __restrict__ tab,
                      uint4* __restrict__ st) {
    if (blockIdx.x == gridDim.x - 1) {
        int a = threadIdx.x;
        if (a < NA) write_tab(thetas, positions, tab, a);
        int a2 = threadIdx.x + 256;
        if (a2 < NA) write_tab(thetas, positions, tab, a2);
        return;
    }
    int idx = blockIdx.x * 256 + threadIdx.x;   // idx = a*PS + p'
    if (idx >= NA * PS) return;
    int a  = idx / PS;
    int pp = idx - a * PS;
    int p0 = pp - 1;
    uint32 r[16];
#pragma unroll
    for (int b = 0; b < NB; ++b) {
        const float* row = sino + ((size_t)b * NA + a) * NP;
        float f0 = (p0 >= 0 && p0 < NP) ? row[p0] : 0.0f;
        float f1 = (pp < NP) ? row[pp] : 0.0f;
        r[b] = pk(f0, f1);
    }
#pragma unroll
    for (int k = 0; k < 4; ++k)
        st[(size_t)k * (NA * PS) + idx] =
            make_uint4(r[4 * k], r[4 * k + 1], r[4 * k + 2], r[4 * k + 3]);
}

// One thread = one (x,y) pixel, 8 batches (blockIdx.z picks the half).
// 2048 blocks -> 8 blocks/CU = 32 waves/CU; distance-2 register prefetch
// keeps 4 wave-loads in flight per wave to hide L2/L3 latency.
__launch_bounds__(256, 8)
__global__ void backproject(const uint4* __restrict__ st,
                            const float4* __restrict__ tab,
                            float* __restrict__ out) {
    const int x = blockIdx.x * 16 + threadIdx.x;
    const int y = blockIdx.y * 16 + threadIdx.y;
    const int h = blockIdx.z;                    // batch half: 0 -> b0..7, 1 -> b8..15
    const float xs = (float)x - ((IMG - 1) * 0.5f);
    const float ys = (float)y - ((IMG - 1) * 0.5f);
    const uint4* __restrict__ plA = st + (size_t)(2 * h) * (NA * PS);
    const uint4* __restrict__ plB = st + (size_t)(2 * h + 1) * (NA * PS);

    float acc[8];
#pragma unroll
    for (int j = 0; j < 8; ++j) acc[j] = 0.0f;

    uint4 bufA[3], bufB[3];
    float wb[3];

    // prologue: issue loads for angles 0 and 1
#pragma unroll
    for (int a = 0; a < 2; ++a) {
        const float4 t = tab[a];
        float fidx = fmaf(xs, t.x, fmaf(ys, t.y, t.z));
        fidx = fminf(fmaxf(fidx, -1.0f), 512.0f);
        const float fl = floorf(fidx);
        wb[a] = fidx - fl;
        const int idx = a * PS + ((int)fl + 1);
        bufA[a] = plA[idx];
        bufB[a] = plB[idx];
    }

#pragma unroll 3
    for (int a = 0; a < NA; ++a) {
        const int cur = a % 3;
        const int nxt = (a + 2) % 3;
        // prefetch angle a+2 (clamped; extra loads at the tail are harmless)
        {
            const int ap = (a + 2 < NA) ? (a + 2) : (NA - 1);
            const float4 t = tab[ap];
            float fidx = fmaf(xs, t.x, fmaf(ys, t.y, t.z));
            fidx = fminf(fmaxf(fidx, -1.0f), 512.0f);
            const float fl = floorf(fidx);
            wb[nxt] = fidx - fl;
            const int idx = ap * PS + ((int)fl + 1);
            bufA[nxt] = plA[idx];
            bufB[nxt] = plB[idx];
        }
        // consume angle a
        const float w = wb[cur];
        const half2 wp = u2h(pk(1.0f - w, w));
        const uint4 d0 = bufA[cur];
        const uint4 d1 = bufB[cur];
        acc[0] = dot2(wp, u2h(d0.x), acc[0]);
        acc[1] = dot2(wp, u2h(d0.y), acc[1]);
        acc[2] = dot2(wp, u2h(d0.z), acc[2]);
        acc[3] = dot2(wp, u2h(d0.w), acc[3]);
        acc[4] = dot2(wp, u2h(d1.x), acc[4]);
        acc[5] = dot2(wp, u2h(d1.y), acc[5]);
        acc[6] = dot2(wp, u2h(d1.z), acc[6]);
        acc[7] = dot2(wp, u2h(d1.w), acc[7]);
    }

    const size_t pix = (size_t)y * IMG + x;
#pragma unroll
    for (int j = 0; j < 8; ++j)
        out[(size_t)(8 * h + j) * (IMG * IMG) + pix] = acc[j];
}

extern "C" void kernel_launch(void* const* d_in, const int* in_sizes, int n_in,
                              void* d_out, int out_size, void* d_ws, size_t ws_size,
                              hipStream_t stream) {
    const float* sino      = (const float*)d_in[0];
    const float* thetas    = (const float*)d_in[1];
    const float* positions = (const float*)d_in[2];
    float* out = (float*)d_out;

    float4* tab = (float4*)d_ws;                     // 360 * 16 B
    uint4*  st  = (uint4*)((char*)d_ws + 8192);      // 4 planes * 2.96 MB = 11.84 MB

    const int nb = (NA * PS + 255) / 256 + 1;        // +1 block computes tab
    stage<<<dim3(nb), dim3(256), 0, stream>>>(sino, thetas, positions, tab, st);
    backproject<<<dim3(IMG / 16, IMG / 16, 2), dim3(16, 16), 0, stream>>>(st, tab, out);
}